// Round 1
// baseline (300.498 us; speedup 1.0000x reference)
//
#include <hip/hip_runtime.h>
#include <math.h>

#define NUM_CITIES 88
#define NUM_YEARS 6
#define N_ROWS 200000

// derived
#define COL4 (NUM_CITIES / 4)                 // 22 float4 groups per row
#define TOT4 (N_ROWS * COL4)                  // 4,400,000 float4 elements in G/D/w
#define DIFF_N (N_ROWS * NUM_YEARS)           // 1,200,000 elements in U/out

// workspace layout (floats)
#define IDX_COL 0        // [0..87] per-column sum(|G|)
#define IDX_DIFF 88      // sum((U-out)^2) over first 5 cols
#define IDX_R2   89      // sum((G - w*D)^2)
#define IDX_W2   90      // sum(w^2)
#define IDX_NEG  91      // sum(min(G,0))
#define WS_FLOATS 92

// Main streaming pass. Grid-stride in float4 units with stride % 22 == 0 so
// each thread's 4-column group is FIXED -> column L1 partials live in registers.
__global__ __launch_bounds__(256) void loss_main(
    const float* __restrict__ G,
    const float* __restrict__ outm,
    const float* __restrict__ U,
    const float* __restrict__ D,
    const float* __restrict__ w,
    float* __restrict__ ws)
{
    __shared__ float scol[NUM_CITIES];
    __shared__ float ssum[4];   // diff, r2, w2, neg

    const int tid = threadIdx.x;
    const int gtid = blockIdx.x * blockDim.x + tid;
    const int nthreads = gridDim.x * blockDim.x;   // 360448, divisible by 22

    const int c0 = (gtid % COL4) * 4;   // fixed first column of this thread's group

    const float4* __restrict__ G4 = (const float4*)G;
    const float4* __restrict__ D4 = (const float4*)D;
    const float4* __restrict__ W4 = (const float4*)w;

    float ca0 = 0.f, ca1 = 0.f, ca2 = 0.f, ca3 = 0.f;  // |G| column partials
    float s_r2 = 0.f, s_w2 = 0.f, s_neg = 0.f;

    for (int i = gtid; i < TOT4; i += nthreads) {
        float4 g = G4[i];
        float4 d = D4[i];
        float4 v = W4[i];

        ca0 += fabsf(g.x); ca1 += fabsf(g.y); ca2 += fabsf(g.z); ca3 += fabsf(g.w);

        float r0 = g.x - v.x * d.x;
        float r1 = g.y - v.y * d.y;
        float r2 = g.z - v.z * d.z;
        float r3 = g.w - v.w * d.w;
        s_r2 += r0 * r0 + r1 * r1 + r2 * r2 + r3 * r3;
        s_w2 += v.x * v.x + v.y * v.y + v.z * v.z + v.w * v.w;
        s_neg += fminf(g.x, 0.f) + fminf(g.y, 0.f) + fminf(g.z, 0.f) + fminf(g.w, 0.f);
    }

    // (U - out)^2 over first NUM_YEARS-1 columns
    float s_diff = 0.f;
    for (int i = gtid; i < DIFF_N; i += nthreads) {
        int c = i % NUM_YEARS;
        float dd = U[i] - outm[i];
        s_diff += (c < NUM_YEARS - 1) ? dd * dd : 0.f;
    }

    // ---- block-level reduction ----
    if (tid < NUM_CITIES) scol[tid] = 0.f;
    if (tid < 4) ssum[tid] = 0.f;
    __syncthreads();

    // column partials: 4 shared atomics per thread
    atomicAdd(&scol[c0 + 0], ca0);
    atomicAdd(&scol[c0 + 1], ca1);
    atomicAdd(&scol[c0 + 2], ca2);
    atomicAdd(&scol[c0 + 3], ca3);

    // scalar partials: wave shuffle reduce (wave = 64), then shared atomic per wave
    for (int off = 32; off > 0; off >>= 1) {
        s_diff += __shfl_down(s_diff, off);
        s_r2   += __shfl_down(s_r2, off);
        s_w2   += __shfl_down(s_w2, off);
        s_neg  += __shfl_down(s_neg, off);
    }
    if ((tid & 63) == 0) {
        atomicAdd(&ssum[0], s_diff);
        atomicAdd(&ssum[1], s_r2);
        atomicAdd(&ssum[2], s_w2);
        atomicAdd(&ssum[3], s_neg);
    }
    __syncthreads();

    if (tid < NUM_CITIES) atomicAdd(&ws[IDX_COL + tid], scol[tid]);
    if (tid == 0) {
        atomicAdd(&ws[IDX_DIFF], ssum[0]);
        atomicAdd(&ws[IDX_R2],   ssum[1]);
        atomicAdd(&ws[IDX_W2],   ssum[2]);
        atomicAdd(&ws[IDX_NEG],  ssum[3]);
    }
}

// Combine: loss = diff + 1e-4 * sum(log(col)) + 100 * r2 + 0.01 * w2 + 100 * neg
__global__ __launch_bounds__(128) void loss_finalize(
    const float* __restrict__ ws, float* __restrict__ out)
{
    __shared__ float sh[2];
    const int tid = threadIdx.x;

    float v = 0.f;
    if (tid < NUM_CITIES) v = logf(ws[IDX_COL + tid]);
    for (int off = 32; off > 0; off >>= 1) v += __shfl_down(v, off);
    if (tid == 0)  sh[0] = v;
    if (tid == 64) sh[1] = v;
    __syncthreads();

    if (tid == 0) {
        float lgg = sh[0] + sh[1];
        float loss = ws[IDX_DIFF]
                   + 1e-4f * lgg
                   + 100.f * ws[IDX_R2]
                   + 0.01f * ws[IDX_W2]
                   + 100.f * ws[IDX_NEG];
        out[0] = loss;
    }
}

extern "C" void kernel_launch(void* const* d_in, const int* in_sizes, int n_in,
                              void* d_out, int out_size, void* d_ws, size_t ws_size,
                              hipStream_t stream) {
    const float* G    = (const float*)d_in[0];
    const float* outm = (const float*)d_in[1];
    const float* U    = (const float*)d_in[2];
    // d_in[3] = V, unused by the reference
    const float* D    = (const float*)d_in[4];
    const float* w    = (const float*)d_in[5];
    float* out = (float*)d_out;
    float* ws  = (float*)d_ws;

    // ws is re-poisoned to 0xAA before every timed launch — zero the part we use
    hipMemsetAsync(ws, 0, WS_FLOATS * sizeof(float), stream);

    // 1408 blocks * 256 threads = 360448 threads; 360448 % 22 == 0 (fixed col group)
    loss_main<<<1408, 256, 0, stream>>>(G, outm, U, D, w, ws);
    loss_finalize<<<1, 128, 0, stream>>>(ws, out);
}

// Round 2
// 269.918 us; speedup vs baseline: 1.1133x; 1.1133x over previous
//
#include <hip/hip_runtime.h>
#include <math.h>

#define NUM_CITIES 88
#define NUM_YEARS 6
#define N_ROWS 200000

#define COL4 (NUM_CITIES / 4)            // 22 float4 groups per row
#define TOT4 (N_ROWS * COL4)             // 4,400,000 float4 elems in G/D/w
#define DIFF2 (N_ROWS * NUM_YEARS / 2)   // 600,000 float2 elems in U/out

#define NBLK 1936                        // grid size; NBLK*256 % 22 == 0
#define NTHREADS (NBLK * 256)            // 495616
#define NPART 92                         // 88 colsums + 4 scalars per block

// Per-block partial layout in ws: ws[bid*92 + k]
//   k in [0,88): per-column sum(|G|)
//   k==88: sum((U-out)^2, first 5 cols)   k==89: sum((G-w*D)^2)
//   k==90: sum(w^2)                       k==91: sum(min(G,0))

__global__ __launch_bounds__(256) void loss_main(
    const float* __restrict__ G,
    const float* __restrict__ outm,
    const float* __restrict__ U,
    const float* __restrict__ D,
    const float* __restrict__ w,
    float* __restrict__ ws)
{
    __shared__ float scol[NUM_CITIES];
    __shared__ float ssum[4];

    const int tid = threadIdx.x;
    const int gtid = blockIdx.x * blockDim.x + tid;
    const int c0 = (gtid % COL4) * 4;    // fixed column group (stride % 22 == 0)

    const float4* __restrict__ G4 = (const float4*)G;
    const float4* __restrict__ D4 = (const float4*)D;
    const float4* __restrict__ W4 = (const float4*)w;

    float ca0 = 0.f, ca1 = 0.f, ca2 = 0.f, ca3 = 0.f;
    float s_r2 = 0.f, s_w2 = 0.f, s_neg = 0.f;

    #pragma unroll 2
    for (int i = gtid; i < TOT4; i += NTHREADS) {
        float4 g = G4[i];
        float4 d = D4[i];
        float4 v = W4[i];

        ca0 += fabsf(g.x); ca1 += fabsf(g.y); ca2 += fabsf(g.z); ca3 += fabsf(g.w);

        float r0 = g.x - v.x * d.x;
        float r1 = g.y - v.y * d.y;
        float r2 = g.z - v.z * d.z;
        float r3 = g.w - v.w * d.w;
        s_r2 += r0 * r0 + r1 * r1 + r2 * r2 + r3 * r3;
        s_w2 += v.x * v.x + v.y * v.y + v.z * v.z + v.w * v.w;
        s_neg += fminf(g.x, 0.f) + fminf(g.y, 0.f) + fminf(g.z, 0.f) + fminf(g.w, 0.f);
    }

    // (U - out)^2 over first 5 of every 6 columns, float2-vectorized
    const float2* __restrict__ U2 = (const float2*)U;
    const float2* __restrict__ O2 = (const float2*)outm;
    float s_diff = 0.f;
    for (int i = gtid; i < DIFF2; i += NTHREADS) {
        float2 u = U2[i];
        float2 o = O2[i];
        float dx = u.x - o.x;
        float dy = u.y - o.y;
        s_diff += dx * dx + ((i % 3 != 2) ? dy * dy : 0.f);
    }

    // ---- block-level reduction (LDS only, no global atomics) ----
    if (tid < NUM_CITIES) scol[tid] = 0.f;
    if (tid < 4) ssum[tid] = 0.f;
    __syncthreads();

    atomicAdd(&scol[c0 + 0], ca0);
    atomicAdd(&scol[c0 + 1], ca1);
    atomicAdd(&scol[c0 + 2], ca2);
    atomicAdd(&scol[c0 + 3], ca3);

    for (int off = 32; off > 0; off >>= 1) {
        s_diff += __shfl_down(s_diff, off);
        s_r2   += __shfl_down(s_r2, off);
        s_w2   += __shfl_down(s_w2, off);
        s_neg  += __shfl_down(s_neg, off);
    }
    if ((tid & 63) == 0) {
        atomicAdd(&ssum[0], s_diff);
        atomicAdd(&ssum[1], s_r2);
        atomicAdd(&ssum[2], s_w2);
        atomicAdd(&ssum[3], s_neg);
    }
    __syncthreads();

    // plain coalesced store of this block's 92 partials
    float* dst = ws + (size_t)blockIdx.x * NPART;
    if (tid < NUM_CITIES) dst[tid] = scol[tid];
    else if (tid < NPART)  dst[tid] = ssum[tid - NUM_CITIES];
}

// Reduce 1936 x 92 partials; loss = diff + 1e-4*sum(log(col)) + 100*r2 + 0.01*w2 + 100*neg
__global__ __launch_bounds__(1024) void loss_finalize(
    const float* __restrict__ ws, float* __restrict__ out)
{
    __shared__ float scomb[NPART];
    __shared__ float sloss;

    const int t = threadIdx.x;
    if (t < NPART) scomb[t] = 0.f;
    if (t == 0) sloss = 0.f;
    __syncthreads();

    if (t < NPART * 11) {               // 1012 active threads, 11 slices per column
        const int c = t % NPART;
        const int s = t / NPART;
        float acc = 0.f;
        for (int b = s; b < NBLK; b += 11) acc += ws[(size_t)b * NPART + c];
        atomicAdd(&scomb[c], acc);
    }
    __syncthreads();

    float term = 0.f;
    if (t < NUM_CITIES)      term = 1e-4f * logf(scomb[t]);
    else if (t == 88)        term = scomb[88];           // diff
    else if (t == 89)        term = 100.f * scomb[89];   // r2 * sg^2/se^2
    else if (t == 90)        term = 0.01f * scomb[90];   // w2 * se^2/sw^2
    else if (t == 91)        term = 100.f * scomb[91];   // neg penalty
    if (t < NPART) atomicAdd(&sloss, term);
    __syncthreads();

    if (t == 0) out[0] = sloss;
}

extern "C" void kernel_launch(void* const* d_in, const int* in_sizes, int n_in,
                              void* d_out, int out_size, void* d_ws, size_t ws_size,
                              hipStream_t stream) {
    const float* G    = (const float*)d_in[0];
    const float* outm = (const float*)d_in[1];
    const float* U    = (const float*)d_in[2];
    // d_in[3] = V, unused by the reference
    const float* D    = (const float*)d_in[4];
    const float* w    = (const float*)d_in[5];
    float* out = (float*)d_out;
    float* ws  = (float*)d_ws;

    // All ws slots we read are unconditionally written by loss_main -> no memset.
    loss_main<<<NBLK, 256, 0, stream>>>(G, outm, U, D, w, ws);
    loss_finalize<<<1, 1024, 0, stream>>>(ws, out);
}

// Round 3
// 224.786 us; speedup vs baseline: 1.3368x; 1.2008x over previous
//
#include <hip/hip_runtime.h>
#include <math.h>

#define NUM_CITIES 88
#define NUM_YEARS 6
#define N_ROWS 200000

#define COL4 (NUM_CITIES / 4)            // 22 float4 groups per row
#define TOT4 (N_ROWS * COL4)             // 4,400,000 float4 elems in G/D/w
#define DIFF2 (N_ROWS * NUM_YEARS / 2)   // 600,000 float2 elems in U/out

#define NBLK 1936                        // 1936 = 2^4 * 11^2 -> NTHREADS % 22 == 0
#define NTHREADS (NBLK * 256)            // 495616
#define NPART 92                         // 88 colsums + 4 scalars per block

// 8 guaranteed iterations per thread: gtid + 7*NTHREADS <= 3,964,927 < TOT4.
// Tail (9th) iteration only for gtid < TOT4 - 8*NTHREADS = 435,072.
#define TAIL_CUT (TOT4 - 8 * NTHREADS)

// ws layout: [0 .. NBLK*NPART) per-block partials; [NBLK*NPART .. +NPART) stage-2 sums
#define WS2_OFF (NBLK * NPART)

__global__ __launch_bounds__(256) void loss_main(
    const float* __restrict__ G,
    const float* __restrict__ outm,
    const float* __restrict__ U,
    const float* __restrict__ D,
    const float* __restrict__ w,
    float* __restrict__ ws)
{
    __shared__ float scol[NUM_CITIES];
    __shared__ float ssum[4];

    const int tid = threadIdx.x;
    const int gtid = blockIdx.x * blockDim.x + tid;
    const int c0 = (gtid % COL4) * 4;    // fixed column group (NTHREADS % 22 == 0)

    const float4* __restrict__ G4 = (const float4*)G;
    const float4* __restrict__ D4 = (const float4*)D;
    const float4* __restrict__ W4 = (const float4*)w;

    // ---- issue all 24 loads for the 8 guaranteed iterations ----
    float4 g0 = G4[gtid + 0 * NTHREADS], g1 = G4[gtid + 1 * NTHREADS];
    float4 g2 = G4[gtid + 2 * NTHREADS], g3 = G4[gtid + 3 * NTHREADS];
    float4 g4 = G4[gtid + 4 * NTHREADS], g5 = G4[gtid + 5 * NTHREADS];
    float4 g6 = G4[gtid + 6 * NTHREADS], g7 = G4[gtid + 7 * NTHREADS];
    float4 d0 = D4[gtid + 0 * NTHREADS], d1 = D4[gtid + 1 * NTHREADS];
    float4 d2 = D4[gtid + 2 * NTHREADS], d3 = D4[gtid + 3 * NTHREADS];
    float4 d4 = D4[gtid + 4 * NTHREADS], d5 = D4[gtid + 5 * NTHREADS];
    float4 d6 = D4[gtid + 6 * NTHREADS], d7 = D4[gtid + 7 * NTHREADS];
    float4 v0 = W4[gtid + 0 * NTHREADS], v1 = W4[gtid + 1 * NTHREADS];
    float4 v2 = W4[gtid + 2 * NTHREADS], v3 = W4[gtid + 3 * NTHREADS];
    float4 v4 = W4[gtid + 4 * NTHREADS], v5 = W4[gtid + 5 * NTHREADS];
    float4 v6 = W4[gtid + 6 * NTHREADS], v7 = W4[gtid + 7 * NTHREADS];

    float ca0 = 0.f, ca1 = 0.f, ca2 = 0.f, ca3 = 0.f;
    float s_r2 = 0.f, s_w2 = 0.f, s_neg = 0.f;

#define ACC(g, d, v)                                                          \
    {                                                                         \
        ca0 += fabsf(g.x); ca1 += fabsf(g.y);                                 \
        ca2 += fabsf(g.z); ca3 += fabsf(g.w);                                 \
        float r0 = g.x - v.x * d.x, r1 = g.y - v.y * d.y;                     \
        float r2 = g.z - v.z * d.z, r3 = g.w - v.w * d.w;                     \
        s_r2 += r0 * r0 + r1 * r1 + r2 * r2 + r3 * r3;                        \
        s_w2 += v.x * v.x + v.y * v.y + v.z * v.z + v.w * v.w;                \
        s_neg += fminf(g.x, 0.f) + fminf(g.y, 0.f)                            \
               + fminf(g.z, 0.f) + fminf(g.w, 0.f);                           \
    }

    ACC(g0, d0, v0) ACC(g1, d1, v1) ACC(g2, d2, v2) ACC(g3, d3, v3)
    ACC(g4, d4, v4) ACC(g5, d5, v5) ACC(g6, d6, v6) ACC(g7, d7, v7)

    // tail iteration (same column group: stride preserves gtid % 22)
    if (gtid < TAIL_CUT) {
        float4 g = G4[gtid + 8 * NTHREADS];
        float4 d = D4[gtid + 8 * NTHREADS];
        float4 v = W4[gtid + 8 * NTHREADS];
        ACC(g, d, v)
    }
#undef ACC

    // ---- (U - out)^2 over first 5 of every 6 columns, float2-vectorized ----
    const float2* __restrict__ U2 = (const float2*)U;
    const float2* __restrict__ O2 = (const float2*)outm;
    float s_diff = 0.f;
    {
        float2 u = U2[gtid], o = O2[gtid];
        float dx = u.x - o.x, dy = u.y - o.y;
        s_diff += dx * dx + ((gtid % 3 != 2) ? dy * dy : 0.f);
        const int i2 = gtid + NTHREADS;
        if (i2 < DIFF2) {
            float2 u2 = U2[i2], o2 = O2[i2];
            float ex = u2.x - o2.x, ey = u2.y - o2.y;
            s_diff += ex * ex + ((i2 % 3 != 2) ? ey * ey : 0.f);
        }
    }

    // ---- block-level reduction (LDS only) ----
    if (tid < NUM_CITIES) scol[tid] = 0.f;
    if (tid < 4) ssum[tid] = 0.f;
    __syncthreads();

    atomicAdd(&scol[c0 + 0], ca0);
    atomicAdd(&scol[c0 + 1], ca1);
    atomicAdd(&scol[c0 + 2], ca2);
    atomicAdd(&scol[c0 + 3], ca3);

    for (int off = 32; off > 0; off >>= 1) {
        s_diff += __shfl_down(s_diff, off);
        s_r2   += __shfl_down(s_r2, off);
        s_w2   += __shfl_down(s_w2, off);
        s_neg  += __shfl_down(s_neg, off);
    }
    if ((tid & 63) == 0) {
        atomicAdd(&ssum[0], s_diff);
        atomicAdd(&ssum[1], s_r2);
        atomicAdd(&ssum[2], s_w2);
        atomicAdd(&ssum[3], s_neg);
    }
    __syncthreads();

    float* dst = ws + (size_t)blockIdx.x * NPART;
    if (tid < NUM_CITIES) dst[tid] = scol[tid];
    else if (tid < NPART)  dst[tid] = ssum[tid - NUM_CITIES];
}

// Stage A: block k sums partial k over all NBLK blocks -> ws[WS2_OFF + k]
__global__ __launch_bounds__(256) void loss_reduce(float* __restrict__ ws)
{
    const int k = blockIdx.x;
    const int t = threadIdx.x;
    float acc = 0.f;
    for (int b = t; b < NBLK; b += 256)
        acc += ws[(size_t)b * NPART + k];
    for (int off = 32; off > 0; off >>= 1) acc += __shfl_down(acc, off);
    __shared__ float s[4];
    if ((t & 63) == 0) s[t >> 6] = acc;
    __syncthreads();
    if (t == 0) ws[WS2_OFF + k] = s[0] + s[1] + s[2] + s[3];
}

// Stage B: loss = diff + 1e-4*sum(log(col)) + 100*r2 + 0.01*w2 + 100*neg
__global__ __launch_bounds__(128) void loss_finalize(
    const float* __restrict__ ws, float* __restrict__ out)
{
    __shared__ float sh[2];
    const int t = threadIdx.x;
    const float* ws2 = ws + WS2_OFF;

    float v = 0.f;
    if (t < NUM_CITIES)      v = 1e-4f * logf(ws2[t]);
    else if (t == 88)        v = ws2[88];           // diff
    else if (t == 89)        v = 100.f * ws2[89];   // r2 * sg^2/se^2
    else if (t == 90)        v = 0.01f * ws2[90];   // w2 * se^2/sw^2
    else if (t == 91)        v = 100.f * ws2[91];   // neg penalty

    for (int off = 32; off > 0; off >>= 1) v += __shfl_down(v, off);
    if (t == 0)  sh[0] = v;
    if (t == 64) sh[1] = v;
    __syncthreads();
    if (t == 0) out[0] = sh[0] + sh[1];
}

extern "C" void kernel_launch(void* const* d_in, const int* in_sizes, int n_in,
                              void* d_out, int out_size, void* d_ws, size_t ws_size,
                              hipStream_t stream) {
    const float* G    = (const float*)d_in[0];
    const float* outm = (const float*)d_in[1];
    const float* U    = (const float*)d_in[2];
    // d_in[3] = V, unused by the reference
    const float* D    = (const float*)d_in[4];
    const float* w    = (const float*)d_in[5];
    float* out = (float*)d_out;
    float* ws  = (float*)d_ws;

    loss_main<<<NBLK, 256, 0, stream>>>(G, outm, U, D, w, ws);
    loss_reduce<<<NPART, 256, 0, stream>>>(ws);
    loss_finalize<<<1, 128, 0, stream>>>(ws, out);
}